// Round 1
// baseline (214.372 us; speedup 1.0000x reference)
//
#include <hip/hip_runtime.h>

#define BB 32
#define NN 1024
#define FF 7
#define HID 256
#define MLPH 64
#define OUTN 8
#define CATN (MLPH + HID + 8)   // 328

// d2 exactly as numpy computes it: fl(fl(dx*dx) + fl(dy*dy)), no fma contraction.
__device__ __forceinline__ float d2_exact(float pj0, float pj1, float pk0, float pk1) {
#pragma clang fp contract(off)
    float dx = pj0 - pk0;
    float dy = pj1 - pk1;
    float a = dx * dx;
    float b = dy * dy;
    return a + b;
}

// Pass 1: degree[b][j] (self-loop included), max d2 per batch, sum of speeds per batch.
// grid = 32*16 blocks, block = 256 = 64 j x 4 k-chunks.
__global__ __launch_bounds__(256) void k_pass1(const float* __restrict__ x,
                                               float* __restrict__ deg,
                                               unsigned* __restrict__ maxd2u,
                                               float* __restrict__ sumsp) {
    __shared__ float l0[NN], l1[NN];
    __shared__ float red[256];
    int blk = blockIdx.x;
    int b  = blk >> 4;
    int jg = blk & 15;
    int tid = threadIdx.x;
    const float* xb = x + b * (NN * FF);
    for (int n = tid; n < NN; n += 256) {
        l0[n] = xb[n * FF + 1];
        l1[n] = xb[n * FF + 2];
    }
    __syncthreads();
    int jloc = tid & 63;
    int kc   = tid >> 6;
    int j = jg * 64 + jloc;
    float pj0 = l0[j], pj1 = l1[j];
    float degp = 0.f, mx = 0.f;
    int k0 = kc * 256;
#pragma unroll 4
    for (int k = k0; k < k0 + 256; ++k) {
        float d2 = d2_exact(pj0, pj1, l0[k], l1[k]);
        degp += (d2 <= 0.09f) ? 1.0f : 0.0f;   // == numpy's sqrt(d2) < 0.3f
        mx = fmaxf(mx, d2);
    }
    red[tid] = degp;
    __syncthreads();
    if (tid < 64) {
        deg[b * NN + j] = red[tid] + red[tid + 64] + red[tid + 128] + red[tid + 192];
    }
    __syncthreads();
    red[tid] = mx;
    __syncthreads();
    for (int s = 128; s > 0; s >>= 1) {
        if (tid < s) red[tid] = fmaxf(red[tid], red[tid + s]);
        __syncthreads();
    }
    if (tid == 0) atomicMax(&maxd2u[b], __float_as_uint(red[0]));
    if (jg == 0) {  // one block per batch does the speed sum
        __syncthreads();
        float sp = 0.f;
        for (int n = tid; n < NN; n += 256) {
            float vx = xb[n * FF + 3], vy = xb[n * FF + 4];
            sp += sqrtf(vx * vx + vy * vy);
        }
        red[tid] = sp;
        __syncthreads();
        for (int s = 128; s > 0; s >>= 1) {
            if (tid < s) red[tid] += red[tid + s];
            __syncthreads();
        }
        if (tid == 0) atomicAdd(&sumsp[b], red[0]);
    }
}

// Pass 2: q0,q1 (dinv-weighted neighbor sums of pts, scaled by dinv[j]) and w[j].
__global__ __launch_bounds__(256) void k_pass2(const float* __restrict__ x,
                                               const float* __restrict__ deg,
                                               float* __restrict__ q0g,
                                               float* __restrict__ q1g,
                                               float* __restrict__ wg) {
    __shared__ float l0[NN], l1[NN], ldi[NN];
    __shared__ float r0[256], r1[256], r2[256];
    int blk = blockIdx.x;
    int b  = blk >> 4;
    int jg = blk & 15;
    int tid = threadIdx.x;
    const float* xb = x + b * (NN * FF);
    for (int n = tid; n < NN; n += 256) {
        l0[n] = xb[n * FF + 1];
        l1[n] = xb[n * FF + 2];
        ldi[n] = 1.0f / sqrtf(deg[b * NN + n]);
    }
    __syncthreads();
    int jloc = tid & 63;
    int kc   = tid >> 6;
    int j = jg * 64 + jloc;
    float pj0 = l0[j], pj1 = l1[j];
    float a0 = 0.f, a1 = 0.f, as = 0.f;
    int k0 = kc * 256;
#pragma unroll 4
    for (int k = k0; k < k0 + 256; ++k) {
        float d2 = d2_exact(pj0, pj1, l0[k], l1[k]);
        float t = (d2 <= 0.09f) ? ldi[k] : 0.0f;
        a0 = fmaf(t, l0[k], a0);
        a1 = fmaf(t, l1[k], a1);
        as += t;
    }
    r0[tid] = a0; r1[tid] = a1; r2[tid] = as;
    __syncthreads();
    if (tid < 64) {
        int jj = jg * 64 + tid;
        float s0 = r0[tid] + r0[tid + 64] + r0[tid + 128] + r0[tid + 192];
        float s1 = r1[tid] + r1[tid + 64] + r1[tid + 128] + r1[tid + 192];
        float ss = r2[tid] + r2[tid + 64] + r2[tid + 128] + r2[tid + 192];
        float dj = ldi[jj];
        q0g[b * NN + jj] = dj * s0;
        q1g[b * NN + jj] = dj * s1;
        wg[b * NN + jj]  = dj * ss * (1.0f / NN);
    }
}

// hsum[b][h] = sum_j w[j] * relu(q0[j]*W1[h,0] + q1[j]*W1[h,1] + b1[h])
// grid = 32*4 (j-chunks of 256), block = 256 (one h per thread), atomicAdd combine.
__global__ __launch_bounds__(256) void k_hsum(const float* __restrict__ q0g,
                                              const float* __restrict__ q1g,
                                              const float* __restrict__ wg,
                                              const float* __restrict__ W1,
                                              const float* __restrict__ b1,
                                              float* __restrict__ hsum) {
    __shared__ float sq0[256], sq1[256], sw[256];
    int blk = blockIdx.x;
    int b  = blk >> 2;
    int jc = blk & 3;
    int tid = threadIdx.x;
    int base = b * NN + jc * 256;
    sq0[tid] = q0g[base + tid];
    sq1[tid] = q1g[base + tid];
    sw[tid]  = wg[base + tid];
    __syncthreads();
    float w10 = W1[tid * 2], w11 = W1[tid * 2 + 1], bb = b1[tid];
    float acc = 0.f;
#pragma unroll 4
    for (int jj = 0; jj < 256; ++jj) {
        float t = fmaf(sq1[jj], w11, fmaf(sq0[jj], w10, bb));
        t = fmaxf(t, 0.f);
        acc = fmaf(sw[jj], t, acc);
    }
    atomicAdd(&hsum[b * HID + tid], acc);
}

// MLP branch: xf2[b][h] for the final concat. grid = 32, block = 256.
__global__ __launch_bounds__(256) void k_mlp(const float* __restrict__ x,
                                             const float* __restrict__ Wm0,
                                             const float* __restrict__ bm0,
                                             const float* __restrict__ Wm1,
                                             const float* __restrict__ bm1,
                                             float* __restrict__ xf2) {
    __shared__ float sx[NN * FF];   // 28 KB
    __shared__ float red[256];
    __shared__ float sh1[64];
    int b = blockIdx.x;
    int tid = threadIdx.x;
    const float* xb = x + b * (NN * FF);
    for (int i = tid; i < NN * FF; i += 256) sx[i] = xb[i];
    __syncthreads();
    int h = tid & 63, c = tid >> 6;
    const int CH = (NN * FF) / 4;   // 1792
    const float4* w4 = (const float4*)(Wm0 + h * (NN * FF) + c * CH);
    const float4* x4 = (const float4*)(sx + c * CH);
    float4 a4 = {0.f, 0.f, 0.f, 0.f};
#pragma unroll 4
    for (int i = 0; i < CH / 4; ++i) {
        float4 wv = w4[i], xv = x4[i];
        a4.x = fmaf(wv.x, xv.x, a4.x);
        a4.y = fmaf(wv.y, xv.y, a4.y);
        a4.z = fmaf(wv.z, xv.z, a4.z);
        a4.w = fmaf(wv.w, xv.w, a4.w);
    }
    red[tid] = (a4.x + a4.y) + (a4.z + a4.w);
    __syncthreads();
    if (tid < 64) {
        float s = red[tid] + red[tid + 64] + red[tid + 128] + red[tid + 192];
        sh1[tid] = fmaxf(s + bm0[tid], 0.f);
    }
    __syncthreads();
    if (tid < 64) {
        float a = bm1[tid];
        const float* w = Wm1 + tid * 64;
#pragma unroll
        for (int k = 0; k < 64; ++k) a = fmaf(w[k], sh1[k], a);
        xf2[b * 64 + tid] = fmaxf(a, 0.f);
    }
}

// Final: meang = W2@hsum+b2; gcn = Wfc@meang+bfc; glo; concat; out = Wp@cat+bp.
__global__ __launch_bounds__(256) void k_final(const float* __restrict__ hsum,
                                               const float* __restrict__ W2,
                                               const float* __restrict__ b2,
                                               const float* __restrict__ Wfc,
                                               const float* __restrict__ bfc,
                                               const float* __restrict__ Wg,
                                               const float* __restrict__ bg,
                                               const float* __restrict__ Wp,
                                               const float* __restrict__ bp,
                                               const float* __restrict__ xf2,
                                               const unsigned* __restrict__ maxd2u,
                                               const float* __restrict__ sumsp,
                                               float* __restrict__ out) {
    __shared__ float hs[HID], mg[HID], cat[CATN];
    int b = blockIdx.x;
    int tid = threadIdx.x;
    hs[tid] = hsum[b * HID + tid];
    if (tid < 64) cat[tid] = xf2[b * 64 + tid];
    if (tid < 8) {
        float avg  = sumsp[b] * (1.0f / NN);
        float dens = 1.0f / sqrtf(__uint_as_float(maxd2u[b]));
        cat[MLPH + HID + tid] =
            fmaxf(fmaf(Wg[tid * 2], avg, fmaf(Wg[tid * 2 + 1], dens, bg[tid])), 0.f);
    }
    __syncthreads();
    {
        float a = b2[tid];
        const float4* w = (const float4*)(W2 + tid * HID);
        const float4* h4 = (const float4*)hs;
#pragma unroll 4
        for (int k = 0; k < HID / 4; ++k) {
            float4 wv = w[k], hv = h4[k];
            a = fmaf(wv.x, hv.x, a); a = fmaf(wv.y, hv.y, a);
            a = fmaf(wv.z, hv.z, a); a = fmaf(wv.w, hv.w, a);
        }
        mg[tid] = a;
    }
    __syncthreads();
    {
        float a = bfc[tid];
        const float4* w = (const float4*)(Wfc + tid * HID);
        const float4* m4 = (const float4*)mg;
#pragma unroll 4
        for (int k = 0; k < HID / 4; ++k) {
            float4 wv = w[k], mv = m4[k];
            a = fmaf(wv.x, mv.x, a); a = fmaf(wv.y, mv.y, a);
            a = fmaf(wv.z, mv.z, a); a = fmaf(wv.w, mv.w, a);
        }
        cat[MLPH + tid] = a;
    }
    __syncthreads();
    if (tid < 8) {
        float a = bp[tid];
        const float* w = Wp + tid * CATN;
#pragma unroll 4
        for (int k = 0; k < CATN; ++k) a = fmaf(w[k], cat[k], a);
        out[b * OUTN + tid] = a;
    }
}

extern "C" void kernel_launch(void* const* d_in, const int* in_sizes, int n_in,
                              void* d_out, int out_size, void* d_ws, size_t ws_size,
                              hipStream_t stream) {
    const float* x   = (const float*)d_in[0];
    const float* W1  = (const float*)d_in[1];
    const float* b1  = (const float*)d_in[2];
    const float* W2  = (const float*)d_in[3];
    const float* b2  = (const float*)d_in[4];
    const float* Wfc = (const float*)d_in[5];
    const float* bfc = (const float*)d_in[6];
    const float* Wg  = (const float*)d_in[7];
    const float* bg  = (const float*)d_in[8];
    const float* Wm0 = (const float*)d_in[9];
    const float* bm0 = (const float*)d_in[10];
    const float* Wm1 = (const float*)d_in[11];
    const float* bm1 = (const float*)d_in[12];
    const float* Wp  = (const float*)d_in[13];
    const float* bp  = (const float*)d_in[14];
    float* out = (float*)d_out;
    float* ws = (float*)d_ws;

    float*    deg    = ws;                     // 32768
    float*    q0     = ws + 32768;             // 32768
    float*    q1     = ws + 65536;             // 32768
    float*    wj     = ws + 98304;             // 32768
    float*    hsum   = ws + 131072;            // 8192
    unsigned* maxd2u = (unsigned*)(ws + 139264); // 32
    float*    sumsp  = ws + 139296;            // 32
    float*    xf2    = ws + 139328;            // 2048

    // zero the atomically-accumulated region (hsum + maxd2 + sumspeed)
    hipMemsetAsync(ws + 131072, 0, (8192 + 64) * sizeof(float), stream);

    k_pass1<<<BB * 16, 256, 0, stream>>>(x, deg, maxd2u, sumsp);
    k_mlp  <<<BB,      256, 0, stream>>>(x, Wm0, bm0, Wm1, bm1, xf2);
    k_pass2<<<BB * 16, 256, 0, stream>>>(x, deg, q0, q1, wj);
    k_hsum <<<BB * 4,  256, 0, stream>>>(q0, q1, wj, W1, b1, hsum);
    k_final<<<BB,      256, 0, stream>>>(hsum, W2, b2, Wfc, bfc, Wg, bg, Wp, bp,
                                         xf2, maxd2u, sumsp, out);
}

// Round 2
// 163.785 us; speedup vs baseline: 1.3089x; 1.3089x over previous
//
#include <hip/hip_runtime.h>

#define BB 32
#define NN 1024
#define FF 7
#define HID 256
#define MLPH 64
#define OUTN 8
#define CATN (MLPH + HID + 8)   // 328

// d2 exactly as numpy computes it: fl(fl(dx*dx) + fl(dy*dy)), no fma contraction.
__device__ __forceinline__ float d2_exact(float pj0, float pj1, float pk0, float pk1) {
#pragma clang fp contract(off)
    float dx = pj0 - pk0;
    float dy = pj1 - pk1;
    float a = dx * dx;
    float b = dy * dy;
    return a + b;
}

__device__ __forceinline__ float wave_sum(float v) {
#pragma unroll
    for (int m = 32; m >= 1; m >>= 1) v += __shfl_xor(v, m, 64);
    return v;
}
__device__ __forceinline__ float wave_max(float v) {
#pragma unroll
    for (int m = 32; m >= 1; m >>= 1) v = fmaxf(v, __shfl_xor(v, m, 64));
    return v;
}

// Pass 1: degree[b][j] (self-loop incl.), max d2 per batch, speed sum per batch.
// grid = 32*16, block = 256 = 64 j x 4 k-chunks. Vectorized b128 LDS reads.
__global__ __launch_bounds__(256) void k_pass1(const float* __restrict__ x,
                                               float* __restrict__ deg,
                                               unsigned* __restrict__ maxd2u,
                                               float* __restrict__ sumsp) {
    __shared__ __align__(16) float l0[NN];
    __shared__ __align__(16) float l1[NN];
    __shared__ float red[256];
    int b  = blockIdx.x >> 4;
    int jg = blockIdx.x & 15;
    int tid = threadIdx.x;
    const float* xb = x + b * (NN * FF);
    for (int n = tid; n < NN; n += 256) {
        l0[n] = xb[n * FF + 1];
        l1[n] = xb[n * FF + 2];
    }
    __syncthreads();
    int jloc = tid & 63;
    int kc   = tid >> 6;
    int j = jg * 64 + jloc;
    float pj0 = l0[j], pj1 = l1[j];
    float degp = 0.f, mx = 0.f;
    const float4* v0p = (const float4*)&l0[kc * 256];
    const float4* v1p = (const float4*)&l1[kc * 256];
#pragma unroll 4
    for (int g = 0; g < 64; ++g) {
        float4 v0 = v0p[g];
        float4 v1 = v1p[g];
        float da = d2_exact(pj0, pj1, v0.x, v1.x);
        float db = d2_exact(pj0, pj1, v0.y, v1.y);
        float dc = d2_exact(pj0, pj1, v0.z, v1.z);
        float dd = d2_exact(pj0, pj1, v0.w, v1.w);
        degp += ((da <= 0.09f) ? 1.0f : 0.0f) + ((db <= 0.09f) ? 1.0f : 0.0f)
              + ((dc <= 0.09f) ? 1.0f : 0.0f) + ((dd <= 0.09f) ? 1.0f : 0.0f);
        mx = fmaxf(mx, fmaxf(fmaxf(da, db), fmaxf(dc, dd)));
    }
    red[tid] = degp;
    __syncthreads();
    if (tid < 64) {
        deg[b * NN + jg * 64 + tid] =
            red[tid] + red[tid + 64] + red[tid + 128] + red[tid + 192];
    }
    mx = wave_max(mx);
    if ((tid & 63) == 0) atomicMax(&maxd2u[b], __float_as_uint(mx));
    if (jg == 0) {  // one block per batch does the speed sum
        float sp = 0.f;
        for (int n = tid; n < NN; n += 256) {
            float vx = xb[n * FF + 3], vy = xb[n * FF + 4];
            sp += sqrtf(vx * vx + vy * vy);
        }
        sp = wave_sum(sp);
        if ((tid & 63) == 0) atomicAdd(&sumsp[b], sp);
    }
}

// Pass 2: q0,q1 (dinv-weighted neighbor sums of pts, scaled by dinv[j]) and w[j].
__global__ __launch_bounds__(256) void k_pass2(const float* __restrict__ x,
                                               const float* __restrict__ deg,
                                               float* __restrict__ q0g,
                                               float* __restrict__ q1g,
                                               float* __restrict__ wg) {
    __shared__ __align__(16) float l0[NN];
    __shared__ __align__(16) float l1[NN];
    __shared__ __align__(16) float ldi[NN];
    __shared__ float r0[256], r1[256], r2[256];
    int b  = blockIdx.x >> 4;
    int jg = blockIdx.x & 15;
    int tid = threadIdx.x;
    const float* xb = x + b * (NN * FF);
    for (int n = tid; n < NN; n += 256) {
        l0[n] = xb[n * FF + 1];
        l1[n] = xb[n * FF + 2];
        ldi[n] = 1.0f / sqrtf(deg[b * NN + n]);
    }
    __syncthreads();
    int jloc = tid & 63;
    int kc   = tid >> 6;
    int j = jg * 64 + jloc;
    float pj0 = l0[j], pj1 = l1[j];
    float a0 = 0.f, a1 = 0.f, as = 0.f;
    const float4* v0p = (const float4*)&l0[kc * 256];
    const float4* v1p = (const float4*)&l1[kc * 256];
    const float4* vdp = (const float4*)&ldi[kc * 256];
#pragma unroll 4
    for (int g = 0; g < 64; ++g) {
        float4 v0 = v0p[g];
        float4 v1 = v1p[g];
        float4 vd = vdp[g];
        float da = d2_exact(pj0, pj1, v0.x, v1.x);
        float db = d2_exact(pj0, pj1, v0.y, v1.y);
        float dc = d2_exact(pj0, pj1, v0.z, v1.z);
        float dd = d2_exact(pj0, pj1, v0.w, v1.w);
        float ta = (da <= 0.09f) ? vd.x : 0.0f;
        float tb = (db <= 0.09f) ? vd.y : 0.0f;
        float tc = (dc <= 0.09f) ? vd.z : 0.0f;
        float td = (dd <= 0.09f) ? vd.w : 0.0f;
        a0 = fmaf(ta, v0.x, a0); a1 = fmaf(ta, v1.x, a1); as += ta;
        a0 = fmaf(tb, v0.y, a0); a1 = fmaf(tb, v1.y, a1); as += tb;
        a0 = fmaf(tc, v0.z, a0); a1 = fmaf(tc, v1.z, a1); as += tc;
        a0 = fmaf(td, v0.w, a0); a1 = fmaf(td, v1.w, a1); as += td;
    }
    r0[tid] = a0; r1[tid] = a1; r2[tid] = as;
    __syncthreads();
    if (tid < 64) {
        int jj = jg * 64 + tid;
        float s0 = r0[tid] + r0[tid + 64] + r0[tid + 128] + r0[tid + 192];
        float s1 = r1[tid] + r1[tid + 64] + r1[tid + 128] + r1[tid + 192];
        float ss = r2[tid] + r2[tid + 64] + r2[tid + 128] + r2[tid + 192];
        float dj = ldi[jj];
        q0g[b * NN + jj] = dj * s0;
        q1g[b * NN + jj] = dj * s1;
        wg[b * NN + jj]  = dj * ss * (1.0f / NN);
    }
}

// hsum[b][h] = sum_j w[j] * relu(q0[j]*W1[h,0] + q1[j]*W1[h,1] + b1[h])
// grid = 32*4 (j-chunks of 256), block = 256 (one h per thread), atomicAdd combine.
__global__ __launch_bounds__(256) void k_hsum(const float* __restrict__ q0g,
                                              const float* __restrict__ q1g,
                                              const float* __restrict__ wg,
                                              const float* __restrict__ W1,
                                              const float* __restrict__ b1,
                                              float* __restrict__ hsum) {
    __shared__ __align__(16) float sq0[256];
    __shared__ __align__(16) float sq1[256];
    __shared__ __align__(16) float sw[256];
    int b  = blockIdx.x >> 2;
    int jc = blockIdx.x & 3;
    int tid = threadIdx.x;
    int base = b * NN + jc * 256;
    sq0[tid] = q0g[base + tid];
    sq1[tid] = q1g[base + tid];
    sw[tid]  = wg[base + tid];
    __syncthreads();
    float w10 = W1[tid * 2], w11 = W1[tid * 2 + 1], bb = b1[tid];
    float acc = 0.f;
    const float4* q0p = (const float4*)sq0;
    const float4* q1p = (const float4*)sq1;
    const float4* wp  = (const float4*)sw;
#pragma unroll 4
    for (int g = 0; g < 64; ++g) {
        float4 q0v = q0p[g], q1v = q1p[g], wv = wp[g];
        acc = fmaf(wv.x, fmaxf(fmaf(q1v.x, w11, fmaf(q0v.x, w10, bb)), 0.f), acc);
        acc = fmaf(wv.y, fmaxf(fmaf(q1v.y, w11, fmaf(q0v.y, w10, bb)), 0.f), acc);
        acc = fmaf(wv.z, fmaxf(fmaf(q1v.z, w11, fmaf(q0v.z, w10, bb)), 0.f), acc);
        acc = fmaf(wv.w, fmaxf(fmaf(q1v.w, w11, fmaf(q0v.w, w10, bb)), 0.f), acc);
    }
    atomicAdd(&hsum[b * HID + tid], acc);
}

// MLP layer 1: one wave per (b,h). grid = 32*16 blocks of 256 (4 waves).
// xf1[b][h] = relu(Wm0[h,:] . x[b,:] + bm0[h])
__global__ __launch_bounds__(256) void k_mlp(const float* __restrict__ x,
                                             const float* __restrict__ Wm0,
                                             const float* __restrict__ bm0,
                                             float* __restrict__ xf1) {
    int b  = blockIdx.x >> 4;
    int hq = blockIdx.x & 15;
    int tid = threadIdx.x;
    int h = hq * 4 + (tid >> 6);
    int lane = tid & 63;
    const float4* wrow = (const float4*)(Wm0 + h * (NN * FF));
    const float4* xrow = (const float4*)(x + b * (NN * FF));
    float4 a4 = {0.f, 0.f, 0.f, 0.f};
#pragma unroll 4
    for (int it = 0; it < 28; ++it) {
        float4 wv = wrow[it * 64 + lane];
        float4 xv = xrow[it * 64 + lane];
        a4.x = fmaf(wv.x, xv.x, a4.x);
        a4.y = fmaf(wv.y, xv.y, a4.y);
        a4.z = fmaf(wv.z, xv.z, a4.z);
        a4.w = fmaf(wv.w, xv.w, a4.w);
    }
    float s = (a4.x + a4.y) + (a4.z + a4.w);
    s = wave_sum(s);
    if (lane == 0) xf1[b * MLPH + h] = fmaxf(s + bm0[h], 0.f);
}

// Final: mlp layer2; meang = W2@hsum+b2; gcn = Wfc@meang+bfc; glo; out = Wp@cat+bp.
__global__ __launch_bounds__(256) void k_final(const float* __restrict__ hsum,
                                               const float* __restrict__ W2,
                                               const float* __restrict__ b2,
                                               const float* __restrict__ Wfc,
                                               const float* __restrict__ bfc,
                                               const float* __restrict__ Wg,
                                               const float* __restrict__ bg,
                                               const float* __restrict__ Wm1,
                                               const float* __restrict__ bm1,
                                               const float* __restrict__ Wp,
                                               const float* __restrict__ bp,
                                               const float* __restrict__ xf1,
                                               const unsigned* __restrict__ maxd2u,
                                               const float* __restrict__ sumsp,
                                               float* __restrict__ out) {
    __shared__ __align__(16) float hs[HID];
    __shared__ __align__(16) float mg[HID];
    __shared__ __align__(16) float cat[CATN];
    __shared__ float sx1[MLPH];
    int b = blockIdx.x;
    int tid = threadIdx.x;
    hs[tid] = hsum[b * HID + tid];
    if (tid < MLPH) sx1[tid] = xf1[b * MLPH + tid];
    if (tid < 8) {
        float avg  = sumsp[b] * (1.0f / NN);
        float dens = 1.0f / sqrtf(__uint_as_float(maxd2u[b]));
        cat[MLPH + HID + tid] =
            fmaxf(fmaf(Wg[tid * 2], avg, fmaf(Wg[tid * 2 + 1], dens, bg[tid])), 0.f);
    }
    __syncthreads();
    if (tid < MLPH) {  // MLP layer 2
        float a = bm1[tid];
        const float* w = Wm1 + tid * MLPH;
#pragma unroll
        for (int k = 0; k < MLPH; ++k) a = fmaf(w[k], sx1[k], a);
        cat[tid] = fmaxf(a, 0.f);
    }
    {
        float a = b2[tid];
        const float4* w = (const float4*)(W2 + tid * HID);
        const float4* h4 = (const float4*)hs;
#pragma unroll 4
        for (int k = 0; k < HID / 4; ++k) {
            float4 wv = w[k], hv = h4[k];
            a = fmaf(wv.x, hv.x, a); a = fmaf(wv.y, hv.y, a);
            a = fmaf(wv.z, hv.z, a); a = fmaf(wv.w, hv.w, a);
        }
        mg[tid] = a;
    }
    __syncthreads();
    {
        float a = bfc[tid];
        const float4* w = (const float4*)(Wfc + tid * HID);
        const float4* m4 = (const float4*)mg;
#pragma unroll 4
        for (int k = 0; k < HID / 4; ++k) {
            float4 wv = w[k], mv = m4[k];
            a = fmaf(wv.x, mv.x, a); a = fmaf(wv.y, mv.y, a);
            a = fmaf(wv.z, mv.z, a); a = fmaf(wv.w, mv.w, a);
        }
        cat[MLPH + tid] = a;
    }
    __syncthreads();
    if (tid < 8) {
        float a = bp[tid];
        const float* w = Wp + tid * CATN;
#pragma unroll 4
        for (int k = 0; k < CATN; ++k) a = fmaf(w[k], cat[k], a);
        out[b * OUTN + tid] = a;
    }
}

extern "C" void kernel_launch(void* const* d_in, const int* in_sizes, int n_in,
                              void* d_out, int out_size, void* d_ws, size_t ws_size,
                              hipStream_t stream) {
    const float* x   = (const float*)d_in[0];
    const float* W1  = (const float*)d_in[1];
    const float* b1  = (const float*)d_in[2];
    const float* W2  = (const float*)d_in[3];
    const float* b2  = (const float*)d_in[4];
    const float* Wfc = (const float*)d_in[5];
    const float* bfc = (const float*)d_in[6];
    const float* Wg  = (const float*)d_in[7];
    const float* bg  = (const float*)d_in[8];
    const float* Wm0 = (const float*)d_in[9];
    const float* bm0 = (const float*)d_in[10];
    const float* Wm1 = (const float*)d_in[11];
    const float* bm1 = (const float*)d_in[12];
    const float* Wp  = (const float*)d_in[13];
    const float* bp  = (const float*)d_in[14];
    float* out = (float*)d_out;
    float* ws = (float*)d_ws;

    float*    deg    = ws;                       // 32768
    float*    q0     = ws + 32768;               // 32768
    float*    q1     = ws + 65536;               // 32768
    float*    wj     = ws + 98304;               // 32768
    float*    hsum   = ws + 131072;              // 8192
    unsigned* maxd2u = (unsigned*)(ws + 139264); // 32
    float*    sumsp  = ws + 139296;              // 32
    float*    xf1    = ws + 139328;              // 2048

    // zero the atomically-accumulated region (hsum + maxd2 + sumspeed)
    hipMemsetAsync(ws + 131072, 0, (8192 + 64) * sizeof(float), stream);

    k_pass1<<<BB * 16, 256, 0, stream>>>(x, deg, maxd2u, sumsp);
    k_mlp  <<<BB * 16, 256, 0, stream>>>(x, Wm0, bm0, xf1);
    k_pass2<<<BB * 16, 256, 0, stream>>>(x, deg, q0, q1, wj);
    k_hsum <<<BB * 4,  256, 0, stream>>>(q0, q1, wj, W1, b1, hsum);
    k_final<<<BB,      256, 0, stream>>>(hsum, W2, b2, Wfc, bfc, Wg, bg,
                                         Wm1, bm1, Wp, bp,
                                         xf1, maxd2u, sumsp, out);
}

// Round 3
// 146.201 us; speedup vs baseline: 1.4663x; 1.1203x over previous
//
#include <hip/hip_runtime.h>

#define BB 32
#define NN 1024
#define FF 7
#define HID 256
#define MLPH 64
#define OUTN 8
#define CATN (MLPH + HID + 8)   // 328

// d2 exactly as numpy computes it: fl(fl(dx*dx) + fl(dy*dy)), no fma contraction.
__device__ __forceinline__ float d2_exact(float pj0, float pj1, float pk0, float pk1) {
#pragma clang fp contract(off)
    float dx = pj0 - pk0;
    float dy = pj1 - pk1;
    float a = dx * dx;
    float b = dy * dy;
    return a + b;
}

__device__ __forceinline__ float wave_sum(float v) {
#pragma unroll
    for (int m = 32; m >= 1; m >>= 1) v += __shfl_xor(v, m, 64);
    return v;
}
__device__ __forceinline__ float wave_max(float v) {
#pragma unroll
    for (int m = 32; m >= 1; m >>= 1) v = fmaxf(v, __shfl_xor(v, m, 64));
    return v;
}

// Pass 1: partial degrees degp[ks][b][j] over k-slice, per-block max d2, speed sum.
// grid = 32*16*4 = 2048 (8 blocks/CU, full occupancy), block = 256.
// b = blk>>6, jg = (blk>>2)&15, ks = blk&3. 64 j per block (one per lane),
// k-slice of 256 split 64 per wave.
__global__ __launch_bounds__(256) void k_pass1(const float* __restrict__ x,
                                               float* __restrict__ degp,
                                               float* __restrict__ bmax,
                                               float* __restrict__ sumsp) {
    __shared__ __align__(16) float l0[256];
    __shared__ __align__(16) float l1[256];
    __shared__ float red[256];
    __shared__ float wred[4];
    int blk = blockIdx.x;
    int b  = blk >> 6;
    int jg = (blk >> 2) & 15;
    int ks = blk & 3;
    int tid  = threadIdx.x;
    int lane = tid & 63;
    int w    = tid >> 6;
    const float* xb = x + b * (NN * FF);
    int n = ks * 256 + tid;
    l0[tid] = xb[n * FF + 1];
    l1[tid] = xb[n * FF + 2];
    int j = jg * 64 + lane;
    float pj0 = xb[j * FF + 1];
    float pj1 = xb[j * FF + 2];
    __syncthreads();
    const float4* v0p = (const float4*)&l0[w * 64];
    const float4* v1p = (const float4*)&l1[w * 64];
    float degv = 0.f, mx = 0.f;
#pragma unroll 4
    for (int g = 0; g < 16; ++g) {
        float4 v0 = v0p[g], v1 = v1p[g];
        float da = d2_exact(pj0, pj1, v0.x, v1.x);
        float db = d2_exact(pj0, pj1, v0.y, v1.y);
        float dc = d2_exact(pj0, pj1, v0.z, v1.z);
        float dd = d2_exact(pj0, pj1, v0.w, v1.w);
        degv += ((da <= 0.09f) ? 1.0f : 0.0f) + ((db <= 0.09f) ? 1.0f : 0.0f)
              + ((dc <= 0.09f) ? 1.0f : 0.0f) + ((dd <= 0.09f) ? 1.0f : 0.0f);
        mx = fmaxf(mx, fmaxf(fmaxf(da, db), fmaxf(dc, dd)));
    }
    red[tid] = degv;
    __syncthreads();
    if (tid < 64) {
        degp[ks * (BB * NN) + b * NN + jg * 64 + tid] =
            red[tid] + red[tid + 64] + red[tid + 128] + red[tid + 192];
    }
    mx = wave_max(mx);
    if (lane == 0) wred[w] = mx;
    __syncthreads();
    if (tid == 0)
        bmax[b * 64 + jg * 4 + ks] =
            fmaxf(fmaxf(wred[0], wred[1]), fmaxf(wred[2], wred[3]));
    if (jg == 0 && ks == 0) {  // one block per batch owns the speed sum
        float sp = 0.f;
        for (int nn = tid; nn < NN; nn += 256) {
            float vx = xb[nn * FF + 3], vy = xb[nn * FF + 4];
            sp += sqrtf(vx * vx + vy * vy);
        }
        sp = wave_sum(sp);
        __syncthreads();
        if (lane == 0) wred[w] = sp;
        __syncthreads();
        if (tid == 0) sumsp[b] = wred[0] + wred[1] + wred[2] + wred[3];
    }
}

// Pass 2: dj-scaled partial sums q0p/q1p/wjp[ks][b][j] over the k-slice.
__global__ __launch_bounds__(256) void k_pass2(const float* __restrict__ x,
                                               const float* __restrict__ degp,
                                               float* __restrict__ q0p,
                                               float* __restrict__ q1p,
                                               float* __restrict__ wjp) {
    __shared__ __align__(16) float l0[256];
    __shared__ __align__(16) float l1[256];
    __shared__ __align__(16) float di[256];
    __shared__ float r0[256], r1[256], r2[256];
    int blk = blockIdx.x;
    int b  = blk >> 6;
    int jg = (blk >> 2) & 15;
    int ks = blk & 3;
    int tid  = threadIdx.x;
    int lane = tid & 63;
    int w    = tid >> 6;
    const float* xb = x + b * (NN * FF);
    int n = ks * 256 + tid;
    l0[tid] = xb[n * FF + 1];
    l1[tid] = xb[n * FF + 2];
    {
        int o = b * NN + n;
        float d = degp[o] + degp[BB * NN + o] + degp[2 * BB * NN + o] + degp[3 * BB * NN + o];
        di[tid] = 1.0f / sqrtf(d);
    }
    int j = jg * 64 + lane;
    float pj0 = xb[j * FF + 1];
    float pj1 = xb[j * FF + 2];
    __syncthreads();
    const float4* v0p = (const float4*)&l0[w * 64];
    const float4* v1p = (const float4*)&l1[w * 64];
    const float4* vdp = (const float4*)&di[w * 64];
    float a0 = 0.f, a1 = 0.f, as = 0.f;
#pragma unroll 4
    for (int g = 0; g < 16; ++g) {
        float4 v0 = v0p[g], v1 = v1p[g], vd = vdp[g];
        float da = d2_exact(pj0, pj1, v0.x, v1.x);
        float db = d2_exact(pj0, pj1, v0.y, v1.y);
        float dc = d2_exact(pj0, pj1, v0.z, v1.z);
        float dd = d2_exact(pj0, pj1, v0.w, v1.w);
        float ta = (da <= 0.09f) ? vd.x : 0.0f;
        float tb = (db <= 0.09f) ? vd.y : 0.0f;
        float tc = (dc <= 0.09f) ? vd.z : 0.0f;
        float td = (dd <= 0.09f) ? vd.w : 0.0f;
        a0 = fmaf(ta, v0.x, a0); a1 = fmaf(ta, v1.x, a1); as += ta;
        a0 = fmaf(tb, v0.y, a0); a1 = fmaf(tb, v1.y, a1); as += tb;
        a0 = fmaf(tc, v0.z, a0); a1 = fmaf(tc, v1.z, a1); as += tc;
        a0 = fmaf(td, v0.w, a0); a1 = fmaf(td, v1.w, a1); as += td;
    }
    r0[tid] = a0; r1[tid] = a1; r2[tid] = as;
    __syncthreads();
    if (tid < 64) {
        int jj = jg * 64 + tid;
        int o = b * NN + jj;
        float d = degp[o] + degp[BB * NN + o] + degp[2 * BB * NN + o] + degp[3 * BB * NN + o];
        float dj = 1.0f / sqrtf(d);
        float s0 = r0[tid] + r0[tid + 64] + r0[tid + 128] + r0[tid + 192];
        float s1 = r1[tid] + r1[tid + 64] + r1[tid + 128] + r1[tid + 192];
        float ss = r2[tid] + r2[tid + 64] + r2[tid + 128] + r2[tid + 192];
        int oo = ks * (BB * NN) + b * NN + jj;
        q0p[oo] = dj * s0;
        q1p[oo] = dj * s1;
        wjp[oo] = dj * ss * (1.0f / NN);
    }
}

// hsum_p[jc][b][h] = sum over 256 j of w[j]*relu(W1.q[j]+b1). grid = 32*4.
__global__ __launch_bounds__(256) void k_hsum(const float* __restrict__ q0p,
                                              const float* __restrict__ q1p,
                                              const float* __restrict__ wjp,
                                              const float* __restrict__ W1,
                                              const float* __restrict__ b1,
                                              float* __restrict__ hsum_p) {
    __shared__ __align__(16) float sq0[256];
    __shared__ __align__(16) float sq1[256];
    __shared__ __align__(16) float sw[256];
    int b  = blockIdx.x >> 2;
    int jc = blockIdx.x & 3;
    int tid = threadIdx.x;
    int o = b * NN + jc * 256 + tid;
    sq0[tid] = q0p[o] + q0p[BB * NN + o] + q0p[2 * BB * NN + o] + q0p[3 * BB * NN + o];
    sq1[tid] = q1p[o] + q1p[BB * NN + o] + q1p[2 * BB * NN + o] + q1p[3 * BB * NN + o];
    sw[tid]  = wjp[o] + wjp[BB * NN + o] + wjp[2 * BB * NN + o] + wjp[3 * BB * NN + o];
    __syncthreads();
    float w10 = W1[tid * 2], w11 = W1[tid * 2 + 1], bb = b1[tid];
    float acc = 0.f;
    const float4* q0v4 = (const float4*)sq0;
    const float4* q1v4 = (const float4*)sq1;
    const float4* wv4  = (const float4*)sw;
#pragma unroll 4
    for (int g = 0; g < 64; ++g) {
        float4 q0v = q0v4[g], q1v = q1v4[g], wv = wv4[g];
        acc = fmaf(wv.x, fmaxf(fmaf(q1v.x, w11, fmaf(q0v.x, w10, bb)), 0.f), acc);
        acc = fmaf(wv.y, fmaxf(fmaf(q1v.y, w11, fmaf(q0v.y, w10, bb)), 0.f), acc);
        acc = fmaf(wv.z, fmaxf(fmaf(q1v.z, w11, fmaf(q0v.z, w10, bb)), 0.f), acc);
        acc = fmaf(wv.w, fmaxf(fmaf(q1v.w, w11, fmaf(q0v.w, w10, bb)), 0.f), acc);
    }
    hsum_p[jc * (BB * HID) + b * HID + tid] = acc;
}

// MLP layer 1: one wave per (b,h). grid = 512 blocks of 256.
__global__ __launch_bounds__(256) void k_mlp(const float* __restrict__ x,
                                             const float* __restrict__ Wm0,
                                             const float* __restrict__ bm0,
                                             float* __restrict__ xf1) {
    int b  = blockIdx.x >> 4;
    int hq = blockIdx.x & 15;
    int tid = threadIdx.x;
    int h = hq * 4 + (tid >> 6);
    int lane = tid & 63;
    const float4* wrow = (const float4*)(Wm0 + h * (NN * FF));
    const float4* xrow = (const float4*)(x + b * (NN * FF));
    float4 a4 = {0.f, 0.f, 0.f, 0.f};
#pragma unroll 7
    for (int it = 0; it < 28; ++it) {
        float4 wv = wrow[it * 64 + lane];
        float4 xv = xrow[it * 64 + lane];
        a4.x = fmaf(wv.x, xv.x, a4.x);
        a4.y = fmaf(wv.y, xv.y, a4.y);
        a4.z = fmaf(wv.z, xv.z, a4.z);
        a4.w = fmaf(wv.w, xv.w, a4.w);
    }
    float s = (a4.x + a4.y) + (a4.z + a4.w);
    s = wave_sum(s);
    if (lane == 0) xf1[b * MLPH + h] = fmaxf(s + bm0[h], 0.f);
}

// Final: reduce partials; mlp layer2; W2/Wfc matvecs; global branch; Wp.
__global__ __launch_bounds__(256) void k_final(const float* __restrict__ hsum_p,
                                               const float* __restrict__ W2,
                                               const float* __restrict__ b2,
                                               const float* __restrict__ Wfc,
                                               const float* __restrict__ bfc,
                                               const float* __restrict__ Wg,
                                               const float* __restrict__ bg,
                                               const float* __restrict__ Wm1,
                                               const float* __restrict__ bm1,
                                               const float* __restrict__ Wp,
                                               const float* __restrict__ bp,
                                               const float* __restrict__ xf1,
                                               const float* __restrict__ bmax,
                                               const float* __restrict__ sumsp,
                                               float* __restrict__ out) {
    __shared__ __align__(16) float hs[HID];
    __shared__ __align__(16) float mg[HID];
    __shared__ __align__(16) float cat[CATN];
    __shared__ float sx1[MLPH];
    __shared__ float smax;
    int b = blockIdx.x;
    int tid = threadIdx.x;
    {
        int o = b * HID + tid;
        hs[tid] = hsum_p[o] + hsum_p[BB * HID + o] + hsum_p[2 * BB * HID + o]
                + hsum_p[3 * BB * HID + o];
    }
    if (tid < MLPH) sx1[tid] = xf1[b * MLPH + tid];
    if (tid < 64) {
        float v = bmax[b * 64 + tid];
        v = wave_max(v);
        if (tid == 0) smax = v;
    }
    __syncthreads();
    if (tid < 8) {
        float avg  = sumsp[b] * (1.0f / NN);
        float dens = 1.0f / sqrtf(smax);
        cat[MLPH + HID + tid] =
            fmaxf(fmaf(Wg[tid * 2], avg, fmaf(Wg[tid * 2 + 1], dens, bg[tid])), 0.f);
    }
    if (tid < MLPH) {  // MLP layer 2
        float a = bm1[tid];
        const float* w = Wm1 + tid * MLPH;
#pragma unroll
        for (int k = 0; k < MLPH; ++k) a = fmaf(w[k], sx1[k], a);
        cat[tid] = fmaxf(a, 0.f);
    }
    {
        float a = b2[tid];
        const float4* w = (const float4*)(W2 + tid * HID);
        const float4* h4 = (const float4*)hs;
#pragma unroll 4
        for (int k = 0; k < HID / 4; ++k) {
            float4 wv = w[k], hv = h4[k];
            a = fmaf(wv.x, hv.x, a); a = fmaf(wv.y, hv.y, a);
            a = fmaf(wv.z, hv.z, a); a = fmaf(wv.w, hv.w, a);
        }
        mg[tid] = a;
    }
    __syncthreads();
    {
        float a = bfc[tid];
        const float4* w = (const float4*)(Wfc + tid * HID);
        const float4* m4 = (const float4*)mg;
#pragma unroll 4
        for (int k = 0; k < HID / 4; ++k) {
            float4 wv = w[k], mv = m4[k];
            a = fmaf(wv.x, mv.x, a); a = fmaf(wv.y, mv.y, a);
            a = fmaf(wv.z, mv.z, a); a = fmaf(wv.w, mv.w, a);
        }
        cat[MLPH + tid] = a;
    }
    __syncthreads();
    if (tid < 8) {
        float a = bp[tid];
        const float* w = Wp + tid * CATN;
#pragma unroll 4
        for (int k = 0; k < CATN; ++k) a = fmaf(w[k], cat[k], a);
        out[b * OUTN + tid] = a;
    }
}

extern "C" void kernel_launch(void* const* d_in, const int* in_sizes, int n_in,
                              void* d_out, int out_size, void* d_ws, size_t ws_size,
                              hipStream_t stream) {
    const float* x   = (const float*)d_in[0];
    const float* W1  = (const float*)d_in[1];
    const float* b1  = (const float*)d_in[2];
    const float* W2  = (const float*)d_in[3];
    const float* b2  = (const float*)d_in[4];
    const float* Wfc = (const float*)d_in[5];
    const float* bfc = (const float*)d_in[6];
    const float* Wg  = (const float*)d_in[7];
    const float* bg  = (const float*)d_in[8];
    const float* Wm0 = (const float*)d_in[9];
    const float* bm0 = (const float*)d_in[10];
    const float* Wm1 = (const float*)d_in[11];
    const float* bm1 = (const float*)d_in[12];
    const float* Wp  = (const float*)d_in[13];
    const float* bp  = (const float*)d_in[14];
    float* out = (float*)d_out;
    float* ws = (float*)d_ws;

    float* degp   = ws;            // 4*32*1024 = 131072
    float* q0p    = ws + 131072;   // 131072
    float* q1p    = ws + 262144;   // 131072
    float* wjp    = ws + 393216;   // 131072
    float* hsum_p = ws + 524288;   // 4*32*256 = 32768
    float* bmax   = ws + 557056;   // 2048
    float* sumsp  = ws + 559104;   // 32
    float* xf1    = ws + 559136;   // 2048
    // every ws cell is written before it is read -> no zero-init, no memset.

    k_pass1<<<BB * 64, 256, 0, stream>>>(x, degp, bmax, sumsp);
    k_mlp  <<<BB * 16, 256, 0, stream>>>(x, Wm0, bm0, xf1);
    k_pass2<<<BB * 64, 256, 0, stream>>>(x, degp, q0p, q1p, wjp);
    k_hsum <<<BB * 4,  256, 0, stream>>>(q0p, q1p, wjp, W1, b1, hsum_p);
    k_final<<<BB,      256, 0, stream>>>(hsum_p, W2, b2, Wfc, bfc, Wg, bg,
                                         Wm1, bm1, Wp, bp,
                                         xf1, bmax, sumsp, out);
}

// Round 4
// 142.487 us; speedup vs baseline: 1.5045x; 1.0261x over previous
//
#include <hip/hip_runtime.h>

#define BB 32
#define NN 1024
#define FF 7
#define HID 256
#define MLPH 64
#define OUTN 8
#define CATN (MLPH + HID + 8)   // 328

__device__ __forceinline__ float wave_sum(float v) {
#pragma unroll
    for (int m = 32; m >= 1; m >>= 1) v += __shfl_xor(v, m, 64);
    return v;
}
__device__ __forceinline__ float wave_max(float v) {
#pragma unroll
    for (int m = 32; m >= 1; m >>= 1) v = fmaxf(v, __shfl_xor(v, m, 64));
    return v;
}

// kA: blocks [0,2048): pass1 — partial degrees degp[ks][b][j], per-block max d2,
//     per-batch speed sum.  blocks [2048,2560): MLP layer-1 GEMV (one wave per (b,h)).
__global__ __launch_bounds__(256) void kA(const float* __restrict__ x,
                                          const float* __restrict__ Wm0,
                                          const float* __restrict__ bm0,
                                          float* __restrict__ degp,
                                          float* __restrict__ bmax,
                                          float* __restrict__ sumsp,
                                          float* __restrict__ xf1) {
    __shared__ __align__(16) float l0[256];
    __shared__ __align__(16) float l1[256];
    __shared__ float red[256];
    __shared__ float wred[4];
    int tid  = threadIdx.x;
    int lane = tid & 63;
    int w    = tid >> 6;
    if (blockIdx.x < 2048) {
        int blk = blockIdx.x;
        int b  = blk >> 6;
        int jg = (blk >> 2) & 15;
        int ks = blk & 3;
        const float* xb = x + b * (NN * FF);
        int n = ks * 256 + tid;
        l0[tid] = xb[n * FF + 1];
        l1[tid] = xb[n * FF + 2];
        int j = jg * 64 + lane;
        float pj0 = xb[j * FF + 1];
        float pj1 = xb[j * FF + 2];
        __syncthreads();
        const float4* v0p = (const float4*)&l0[w * 64];
        const float4* v1p = (const float4*)&l1[w * 64];
        unsigned degv = 0u;
        float mx = 0.f;
#pragma unroll 4
        for (int g = 0; g < 16; ++g) {
            float4 v0 = v0p[g], v1 = v1p[g];
            float dxa = pj0 - v0.x, dya = pj1 - v1.x;
            float dxb = pj0 - v0.y, dyb = pj1 - v1.y;
            float dxc = pj0 - v0.z, dyc = pj1 - v1.z;
            float dxd = pj0 - v0.w, dyd = pj1 - v1.w;
            float da = fmaf(dya, dya, dxa * dxa);
            float db = fmaf(dyb, dyb, dxb * dxb);
            float dc = fmaf(dyc, dyc, dxc * dxc);
            float dd = fmaf(dyd, dyd, dxd * dxd);
            degv += (da <= 0.09f);
            degv += (db <= 0.09f);
            degv += (dc <= 0.09f);
            degv += (dd <= 0.09f);
            mx = fmaxf(fmaxf(mx, fmaxf(da, db)), fmaxf(dc, dd));
        }
        red[tid] = (float)degv;
        __syncthreads();
        if (tid < 64) {
            degp[ks * (BB * NN) + b * NN + jg * 64 + tid] =
                red[tid] + red[tid + 64] + red[tid + 128] + red[tid + 192];
        }
        mx = wave_max(mx);
        if (lane == 0) wred[w] = mx;
        __syncthreads();
        if (tid == 0)
            bmax[b * 64 + jg * 4 + ks] =
                fmaxf(fmaxf(wred[0], wred[1]), fmaxf(wred[2], wred[3]));
        if (jg == 0 && ks == 0) {  // one block per batch owns the speed sum
            float sp = 0.f;
            for (int nn = tid; nn < NN; nn += 256) {
                float vx = xb[nn * FF + 3], vy = xb[nn * FF + 4];
                sp += sqrtf(vx * vx + vy * vy);
            }
            sp = wave_sum(sp);
            __syncthreads();
            if (lane == 0) wred[w] = sp;
            __syncthreads();
            if (tid == 0) sumsp[b] = wred[0] + wred[1] + wred[2] + wred[3];
        }
    } else {
        int blk = blockIdx.x - 2048;
        int b  = blk >> 4;
        int hq = blk & 15;
        int h = hq * 4 + w;
        const float4* wrow = (const float4*)(Wm0 + h * (NN * FF));
        const float4* xrow = (const float4*)(x + b * (NN * FF));
        float4 a4 = {0.f, 0.f, 0.f, 0.f};
#pragma unroll 7
        for (int it = 0; it < 28; ++it) {
            float4 wv = wrow[it * 64 + lane];
            float4 xv = xrow[it * 64 + lane];
            a4.x = fmaf(wv.x, xv.x, a4.x);
            a4.y = fmaf(wv.y, xv.y, a4.y);
            a4.z = fmaf(wv.z, xv.z, a4.z);
            a4.w = fmaf(wv.w, xv.w, a4.w);
        }
        float s = (a4.x + a4.y) + (a4.z + a4.w);
        s = wave_sum(s);
        if (lane == 0) xf1[b * MLPH + h] = fmaxf(s + bm0[h], 0.f);
    }
}

// kB: pass2 — dj-scaled partial sums q0p/q1p/wjp[ks][b][j] over the k-slice.
__global__ __launch_bounds__(256) void kB(const float* __restrict__ x,
                                          const float* __restrict__ degp,
                                          float* __restrict__ q0p,
                                          float* __restrict__ q1p,
                                          float* __restrict__ wjp) {
    __shared__ __align__(16) float l0[256];
    __shared__ __align__(16) float l1[256];
    __shared__ __align__(16) float di[256];
    __shared__ float r0[256], r1[256], r2[256];
    int blk = blockIdx.x;
    int b  = blk >> 6;
    int jg = (blk >> 2) & 15;
    int ks = blk & 3;
    int tid  = threadIdx.x;
    int lane = tid & 63;
    int w    = tid >> 6;
    const float* xb = x + b * (NN * FF);
    int n = ks * 256 + tid;
    l0[tid] = xb[n * FF + 1];
    l1[tid] = xb[n * FF + 2];
    {
        int o = b * NN + n;
        float d = degp[o] + degp[BB * NN + o] + degp[2 * BB * NN + o] + degp[3 * BB * NN + o];
        di[tid] = 1.0f / sqrtf(d);
    }
    int j = jg * 64 + lane;
    float pj0 = xb[j * FF + 1];
    float pj1 = xb[j * FF + 2];
    __syncthreads();
    const float4* v0p = (const float4*)&l0[w * 64];
    const float4* v1p = (const float4*)&l1[w * 64];
    const float4* vdp = (const float4*)&di[w * 64];
    float a0 = 0.f, a1 = 0.f, as = 0.f;
#pragma unroll 4
    for (int g = 0; g < 16; ++g) {
        float4 v0 = v0p[g], v1 = v1p[g], vd = vdp[g];
        float dxa = pj0 - v0.x, dya = pj1 - v1.x;
        float dxb = pj0 - v0.y, dyb = pj1 - v1.y;
        float dxc = pj0 - v0.z, dyc = pj1 - v1.z;
        float dxd = pj0 - v0.w, dyd = pj1 - v1.w;
        float da = fmaf(dya, dya, dxa * dxa);
        float db = fmaf(dyb, dyb, dxb * dxb);
        float dc = fmaf(dyc, dyc, dxc * dxc);
        float dd = fmaf(dyd, dyd, dxd * dxd);
        float ta = (da <= 0.09f) ? vd.x : 0.0f;
        float tb = (db <= 0.09f) ? vd.y : 0.0f;
        float tc = (dc <= 0.09f) ? vd.z : 0.0f;
        float td = (dd <= 0.09f) ? vd.w : 0.0f;
        a0 = fmaf(ta, v0.x, a0); a1 = fmaf(ta, v1.x, a1); as += ta;
        a0 = fmaf(tb, v0.y, a0); a1 = fmaf(tb, v1.y, a1); as += tb;
        a0 = fmaf(tc, v0.z, a0); a1 = fmaf(tc, v1.z, a1); as += tc;
        a0 = fmaf(td, v0.w, a0); a1 = fmaf(td, v1.w, a1); as += td;
    }
    r0[tid] = a0; r1[tid] = a1; r2[tid] = as;
    __syncthreads();
    if (tid < 64) {
        int jj = jg * 64 + tid;
        int o = b * NN + jj;
        float d = degp[o] + degp[BB * NN + o] + degp[2 * BB * NN + o] + degp[3 * BB * NN + o];
        float dj = 1.0f / sqrtf(d);
        float s0 = r0[tid] + r0[tid + 64] + r0[tid + 128] + r0[tid + 192];
        float s1 = r1[tid] + r1[tid + 64] + r1[tid + 128] + r1[tid + 192];
        float ss = r2[tid] + r2[tid + 64] + r2[tid + 128] + r2[tid + 192];
        int oo = ks * (BB * NN) + b * NN + jj;
        q0p[oo] = dj * s0;
        q1p[oo] = dj * s1;
        wjp[oo] = dj * ss * (1.0f / NN);
    }
}

// kC: hsum + epilogue fused. grid = 32 blocks x 1024 threads (one block per batch).
__global__ __launch_bounds__(1024) void kC(const float* __restrict__ q0p,
                                           const float* __restrict__ q1p,
                                           const float* __restrict__ wjp,
                                           const float* __restrict__ W1,
                                           const float* __restrict__ b1,
                                           const float* __restrict__ W2,
                                           const float* __restrict__ b2,
                                           const float* __restrict__ Wfc,
                                           const float* __restrict__ bfc,
                                           const float* __restrict__ Wg,
                                           const float* __restrict__ bg,
                                           const float* __restrict__ Wm1,
                                           const float* __restrict__ bm1,
                                           const float* __restrict__ Wp,
                                           const float* __restrict__ bp,
                                           const float* __restrict__ xf1,
                                           const float* __restrict__ bmax,
                                           const float* __restrict__ sumsp,
                                           float* __restrict__ out) {
    __shared__ __align__(16) float sq0[NN];
    __shared__ __align__(16) float sq1[NN];
    __shared__ __align__(16) float sw[NN];
    __shared__ __align__(16) float hp[4][HID];
    __shared__ __align__(16) float hs[HID];
    __shared__ __align__(16) float mg[HID];
    __shared__ __align__(16) float cat[CATN];
    __shared__ float sx1[MLPH];
    __shared__ float smax;
    int b = blockIdx.x;
    int tid = threadIdx.x;
    // stage A: reduce the 4 k-slice partials for this batch
    {
        int o = b * NN + tid;
        sq0[tid] = q0p[o] + q0p[BB * NN + o] + q0p[2 * BB * NN + o] + q0p[3 * BB * NN + o];
        sq1[tid] = q1p[o] + q1p[BB * NN + o] + q1p[2 * BB * NN + o] + q1p[3 * BB * NN + o];
        sw[tid]  = wjp[o] + wjp[BB * NN + o] + wjp[2 * BB * NN + o] + wjp[3 * BB * NN + o];
    }
    __syncthreads();
    // stage B: hsum partials, 4-way j-parallel (h = tid&255, jq = tid>>8)
    {
        int h  = tid & 255;
        int jq = tid >> 8;
        float w10 = W1[h * 2], w11 = W1[h * 2 + 1], bb = b1[h];
        float acc = 0.f;
        const float4* q0v4 = (const float4*)&sq0[jq * 256];
        const float4* q1v4 = (const float4*)&sq1[jq * 256];
        const float4* wv4  = (const float4*)&sw[jq * 256];
#pragma unroll 4
        for (int g = 0; g < 64; ++g) {
            float4 q0v = q0v4[g], q1v = q1v4[g], wv = wv4[g];
            acc = fmaf(wv.x, fmaxf(fmaf(q1v.x, w11, fmaf(q0v.x, w10, bb)), 0.f), acc);
            acc = fmaf(wv.y, fmaxf(fmaf(q1v.y, w11, fmaf(q0v.y, w10, bb)), 0.f), acc);
            acc = fmaf(wv.z, fmaxf(fmaf(q1v.z, w11, fmaf(q0v.z, w10, bb)), 0.f), acc);
            acc = fmaf(wv.w, fmaxf(fmaf(q1v.w, w11, fmaf(q0v.w, w10, bb)), 0.f), acc);
        }
        hp[jq][h] = acc;
    }
    // stage C inputs that don't depend on hp
    if (tid >= 512 && tid < 576) sx1[tid - 512] = xf1[b * MLPH + (tid - 512)];
    if (tid >= 576 && tid < 640) {
        float v = bmax[b * 64 + (tid - 576)];
        v = wave_max(v);
        if (tid == 576) smax = v;
    }
    __syncthreads();
    if (tid < HID) hs[tid] = hp[0][tid] + hp[1][tid] + hp[2][tid] + hp[3][tid];
    __syncthreads();
    // stage D: W2 matvec (0..255), MLP layer-2 (256..319), global branch (320..327)
    if (tid < HID) {
        float a = b2[tid];
        const float4* wv = (const float4*)(W2 + tid * HID);
        const float4* h4 = (const float4*)hs;
#pragma unroll 4
        for (int k = 0; k < HID / 4; ++k) {
            float4 w4 = wv[k], hv = h4[k];
            a = fmaf(w4.x, hv.x, a); a = fmaf(w4.y, hv.y, a);
            a = fmaf(w4.z, hv.z, a); a = fmaf(w4.w, hv.w, a);
        }
        mg[tid] = a;
    } else if (tid < HID + MLPH) {
        int t = tid - HID;
        float a = bm1[t];
        const float* wv = Wm1 + t * MLPH;
#pragma unroll
        for (int k = 0; k < MLPH; ++k) a = fmaf(wv[k], sx1[k], a);
        cat[t] = fmaxf(a, 0.f);
    } else if (tid < HID + MLPH + 8) {
        int t = tid - HID - MLPH;
        float avg  = sumsp[b] * (1.0f / NN);
        float dens = 1.0f / sqrtf(smax);
        cat[MLPH + HID + t] =
            fmaxf(fmaf(Wg[t * 2], avg, fmaf(Wg[t * 2 + 1], dens, bg[t])), 0.f);
    }
    __syncthreads();
    // stage E: Wfc matvec into cat
    if (tid < HID) {
        float a = bfc[tid];
        const float4* wv = (const float4*)(Wfc + tid * HID);
        const float4* m4 = (const float4*)mg;
#pragma unroll 4
        for (int k = 0; k < HID / 4; ++k) {
            float4 w4 = wv[k], mv = m4[k];
            a = fmaf(w4.x, mv.x, a); a = fmaf(w4.y, mv.y, a);
            a = fmaf(w4.z, mv.z, a); a = fmaf(w4.w, mv.w, a);
        }
        cat[MLPH + tid] = a;
    }
    __syncthreads();
    // stage F: output projection
    if (tid < 8) {
        float a = bp[tid];
        const float* wv = Wp + tid * CATN;
#pragma unroll 4
        for (int k = 0; k < CATN; ++k) a = fmaf(wv[k], cat[k], a);
        out[b * OUTN + tid] = a;
    }
}

extern "C" void kernel_launch(void* const* d_in, const int* in_sizes, int n_in,
                              void* d_out, int out_size, void* d_ws, size_t ws_size,
                              hipStream_t stream) {
    const float* x   = (const float*)d_in[0];
    const float* W1  = (const float*)d_in[1];
    const float* b1  = (const float*)d_in[2];
    const float* W2  = (const float*)d_in[3];
    const float* b2  = (const float*)d_in[4];
    const float* Wfc = (const float*)d_in[5];
    const float* bfc = (const float*)d_in[6];
    const float* Wg  = (const float*)d_in[7];
    const float* bg  = (const float*)d_in[8];
    const float* Wm0 = (const float*)d_in[9];
    const float* bm0 = (const float*)d_in[10];
    const float* Wm1 = (const float*)d_in[11];
    const float* bm1 = (const float*)d_in[12];
    const float* Wp  = (const float*)d_in[13];
    const float* bp  = (const float*)d_in[14];
    float* out = (float*)d_out;
    float* ws = (float*)d_ws;

    float* degp  = ws;            // 4*32*1024 = 131072
    float* q0p   = ws + 131072;   // 131072
    float* q1p   = ws + 262144;   // 131072
    float* wjp   = ws + 393216;   // 131072
    float* bmax  = ws + 524288;   // 2048
    float* sumsp = ws + 526336;   // 32
    float* xf1   = ws + 526368;   // 2048
    // every ws cell is written before it is read -> no zero-init needed.

    kA<<<2560,    256,  0, stream>>>(x, Wm0, bm0, degp, bmax, sumsp, xf1);
    kB<<<BB * 64, 256,  0, stream>>>(x, degp, q0p, q1p, wjp);
    kC<<<BB,      1024, 0, stream>>>(q0p, q1p, wjp, W1, b1, W2, b2, Wfc, bfc,
                                     Wg, bg, Wm1, bm1, Wp, bp,
                                     xf1, bmax, sumsp, out);
}

// Round 5
// 129.856 us; speedup vs baseline: 1.6508x; 1.0973x over previous
//
#include <hip/hip_runtime.h>

#define BB 32
#define NN 1024
#define FF 7
#define HID 256
#define MLPH 64
#define OUTN 8
#define CATN (MLPH + HID + 8)   // 328

__device__ __forceinline__ float wave_sum(float v) {
#pragma unroll
    for (int m = 32; m >= 1; m >>= 1) v += __shfl_xor(v, m, 64);
    return v;
}
__device__ __forceinline__ float wave_max(float v) {
#pragma unroll
    for (int m = 32; m >= 1; m >>= 1) v = fmaxf(v, __shfl_xor(v, m, 64));
    return v;
}

// kA: blocks [0,2048): pass1 — partial degrees degp[ks][b][j], per-block max d2,
//     per-batch speed sum.
//     blocks [2048,2560): MLP layer-1 GEMV (one wave per (b,h)).
//     blocks [2560,2568): weight collapse E = (Wp_gcn@Wfc)@W2 (8 KB), cE[8].
__global__ __launch_bounds__(256) void kA(const float* __restrict__ x,
                                          const float* __restrict__ Wm0,
                                          const float* __restrict__ bm0,
                                          const float* __restrict__ W2,
                                          const float* __restrict__ b2,
                                          const float* __restrict__ Wfc,
                                          const float* __restrict__ bfc,
                                          const float* __restrict__ Wp,
                                          float* __restrict__ degp,
                                          float* __restrict__ bmax,
                                          float* __restrict__ sumsp,
                                          float* __restrict__ xf1,
                                          float* __restrict__ E,
                                          float* __restrict__ cE) {
    __shared__ __align__(16) float l0[256];
    __shared__ __align__(16) float l1[256];
    __shared__ float red[256];
    __shared__ float wred[4];
    int tid  = threadIdx.x;
    int lane = tid & 63;
    int w    = tid >> 6;
    if (blockIdx.x < 2048) {
        int blk = blockIdx.x;
        int b  = blk >> 6;
        int jg = (blk >> 2) & 15;
        int ks = blk & 3;
        const float* xb = x + b * (NN * FF);
        int n = ks * 256 + tid;
        l0[tid] = xb[n * FF + 1];
        l1[tid] = xb[n * FF + 2];
        int j = jg * 64 + lane;
        float pj0 = xb[j * FF + 1];
        float pj1 = xb[j * FF + 2];
        __syncthreads();
        const float4* v0p = (const float4*)&l0[w * 64];
        const float4* v1p = (const float4*)&l1[w * 64];
        unsigned degv = 0u;
        float mx = 0.f;
#pragma unroll 4
        for (int g = 0; g < 16; ++g) {
            float4 v0 = v0p[g], v1 = v1p[g];
            float dxa = pj0 - v0.x, dya = pj1 - v1.x;
            float dxb = pj0 - v0.y, dyb = pj1 - v1.y;
            float dxc = pj0 - v0.z, dyc = pj1 - v1.z;
            float dxd = pj0 - v0.w, dyd = pj1 - v1.w;
            float da = fmaf(dya, dya, dxa * dxa);
            float db = fmaf(dyb, dyb, dxb * dxb);
            float dc = fmaf(dyc, dyc, dxc * dxc);
            float dd = fmaf(dyd, dyd, dxd * dxd);
            degv += (da <= 0.09f);
            degv += (db <= 0.09f);
            degv += (dc <= 0.09f);
            degv += (dd <= 0.09f);
            mx = fmaxf(fmaxf(mx, fmaxf(da, db)), fmaxf(dc, dd));
        }
        red[tid] = (float)degv;
        __syncthreads();
        if (tid < 64) {
            degp[ks * (BB * NN) + b * NN + jg * 64 + tid] =
                red[tid] + red[tid + 64] + red[tid + 128] + red[tid + 192];
        }
        mx = wave_max(mx);
        if (lane == 0) wred[w] = mx;
        __syncthreads();
        if (tid == 0)
            bmax[b * 64 + jg * 4 + ks] =
                fmaxf(fmaxf(wred[0], wred[1]), fmaxf(wred[2], wred[3]));
        if (jg == 0 && ks == 0) {  // one block per batch owns the speed sum
            float sp = 0.f;
            for (int nn = tid; nn < NN; nn += 256) {
                float vx = xb[nn * FF + 3], vy = xb[nn * FF + 4];
                sp += sqrtf(vx * vx + vy * vy);
            }
            sp = wave_sum(sp);
            __syncthreads();
            if (lane == 0) wred[w] = sp;
            __syncthreads();
            if (tid == 0) sumsp[b] = wred[0] + wred[1] + wred[2] + wred[3];
        }
    } else if (blockIdx.x < 2560) {
        int blk = blockIdx.x - 2048;
        int b  = blk >> 4;
        int hq = blk & 15;
        int h = hq * 4 + w;
        const float4* wrow = (const float4*)(Wm0 + h * (NN * FF));
        const float4* xrow = (const float4*)(x + b * (NN * FF));
        float4 a4 = {0.f, 0.f, 0.f, 0.f};
#pragma unroll 7
        for (int it = 0; it < 28; ++it) {
            float4 wv = wrow[it * 64 + lane];
            float4 xv = xrow[it * 64 + lane];
            a4.x = fmaf(wv.x, xv.x, a4.x);
            a4.y = fmaf(wv.y, xv.y, a4.y);
            a4.z = fmaf(wv.z, xv.z, a4.z);
            a4.w = fmaf(wv.w, xv.w, a4.w);
        }
        float s = (a4.x + a4.y) + (a4.z + a4.w);
        s = wave_sum(s);
        if (lane == 0) xf1[b * MLPH + h] = fmaxf(s + bm0[h], 0.f);
    } else {
        // weight collapse, one block per output row o.
        // T[k] = sum_m Wp_gcn[o,m]*Wfc[m,k];  E[o,h] = sum_k T[k]*W2[k,h]
        // cE[o] = sum_k T[k]*b2[k] + sum_m Wp_gcn[o,m]*bfc[m]
        int o = blockIdx.x - 2560;
        // reuse l0 as sWp, l1 as sT, red as reduction scratch
        l0[tid] = Wp[o * CATN + MLPH + tid];
        __syncthreads();
        float a = 0.f;
#pragma unroll 8
        for (int m = 0; m < HID; ++m) a = fmaf(l0[m], Wfc[m * HID + tid], a);
        l1[tid] = a;
        red[tid] = l0[tid] * bfc[tid];
        __syncthreads();
        float e = 0.f;
#pragma unroll 8
        for (int k = 0; k < HID; ++k) e = fmaf(l1[k], W2[k * HID + tid], e);
        E[o * HID + tid] = e;
        float c = fmaf(l1[tid], b2[tid], red[tid]);
        c = wave_sum(c);
        if (lane == 0) wred[w] = c;
        __syncthreads();
        if (tid == 0) cE[o] = wred[0] + wred[1] + wred[2] + wred[3];
    }
}

// kB: pass2 — dj-scaled partial sums q0p/q1p/wjp[ks][b][j] over the k-slice.
__global__ __launch_bounds__(256) void kB(const float* __restrict__ x,
                                          const float* __restrict__ degp,
                                          float* __restrict__ q0p,
                                          float* __restrict__ q1p,
                                          float* __restrict__ wjp) {
    __shared__ __align__(16) float l0[256];
    __shared__ __align__(16) float l1[256];
    __shared__ __align__(16) float di[256];
    __shared__ float r0[256], r1[256], r2[256];
    int blk = blockIdx.x;
    int b  = blk >> 6;
    int jg = (blk >> 2) & 15;
    int ks = blk & 3;
    int tid  = threadIdx.x;
    int lane = tid & 63;
    int w    = tid >> 6;
    const float* xb = x + b * (NN * FF);
    int n = ks * 256 + tid;
    l0[tid] = xb[n * FF + 1];
    l1[tid] = xb[n * FF + 2];
    {
        int o = b * NN + n;
        float d = degp[o] + degp[BB * NN + o] + degp[2 * BB * NN + o] + degp[3 * BB * NN + o];
        di[tid] = 1.0f / sqrtf(d);
    }
    int j = jg * 64 + lane;
    float pj0 = xb[j * FF + 1];
    float pj1 = xb[j * FF + 2];
    __syncthreads();
    const float4* v0p = (const float4*)&l0[w * 64];
    const float4* v1p = (const float4*)&l1[w * 64];
    const float4* vdp = (const float4*)&di[w * 64];
    float a0 = 0.f, a1 = 0.f, as = 0.f;
#pragma unroll 4
    for (int g = 0; g < 16; ++g) {
        float4 v0 = v0p[g], v1 = v1p[g], vd = vdp[g];
        float dxa = pj0 - v0.x, dya = pj1 - v1.x;
        float dxb = pj0 - v0.y, dyb = pj1 - v1.y;
        float dxc = pj0 - v0.z, dyc = pj1 - v1.z;
        float dxd = pj0 - v0.w, dyd = pj1 - v1.w;
        float da = fmaf(dya, dya, dxa * dxa);
        float db = fmaf(dyb, dyb, dxb * dxb);
        float dc = fmaf(dyc, dyc, dxc * dxc);
        float dd = fmaf(dyd, dyd, dxd * dxd);
        float ta = (da <= 0.09f) ? vd.x : 0.0f;
        float tb = (db <= 0.09f) ? vd.y : 0.0f;
        float tc = (dc <= 0.09f) ? vd.z : 0.0f;
        float td = (dd <= 0.09f) ? vd.w : 0.0f;
        a0 = fmaf(ta, v0.x, a0); a1 = fmaf(ta, v1.x, a1); as += ta;
        a0 = fmaf(tb, v0.y, a0); a1 = fmaf(tb, v1.y, a1); as += tb;
        a0 = fmaf(tc, v0.z, a0); a1 = fmaf(tc, v1.z, a1); as += tc;
        a0 = fmaf(td, v0.w, a0); a1 = fmaf(td, v1.w, a1); as += td;
    }
    r0[tid] = a0; r1[tid] = a1; r2[tid] = as;
    __syncthreads();
    if (tid < 64) {
        int jj = jg * 64 + tid;
        int o = b * NN + jj;
        float d = degp[o] + degp[BB * NN + o] + degp[2 * BB * NN + o] + degp[3 * BB * NN + o];
        float dj = 1.0f / sqrtf(d);
        float s0 = r0[tid] + r0[tid + 64] + r0[tid + 128] + r0[tid + 192];
        float s1 = r1[tid] + r1[tid + 64] + r1[tid + 128] + r1[tid + 192];
        float ss = r2[tid] + r2[tid + 64] + r2[tid + 128] + r2[tid + 192];
        int oo = ks * (BB * NN) + b * NN + jj;
        q0p[oo] = dj * s0;
        q1p[oo] = dj * s1;
        wjp[oo] = dj * ss * (1.0f / NN);
    }
}

// kF: hsum + collapsed epilogue. grid = 32 blocks x 1024 threads.
// Per-block global reads: ~48 KB partials + 8 KB E + 16 KB Wm1 + small — no W2/Wfc.
__global__ __launch_bounds__(1024) void kF(const float* __restrict__ q0p,
                                           const float* __restrict__ q1p,
                                           const float* __restrict__ wjp,
                                           const float* __restrict__ W1,
                                           const float* __restrict__ b1,
                                           const float* __restrict__ Wg,
                                           const float* __restrict__ bg,
                                           const float* __restrict__ Wm1,
                                           const float* __restrict__ bm1,
                                           const float* __restrict__ Wp,
                                           const float* __restrict__ bp,
                                           const float* __restrict__ xf1,
                                           const float* __restrict__ bmax,
                                           const float* __restrict__ sumsp,
                                           const float* __restrict__ E,
                                           const float* __restrict__ cE,
                                           float* __restrict__ out) {
    __shared__ __align__(16) float sq0[NN];
    __shared__ __align__(16) float sq1[NN];
    __shared__ __align__(16) float sw[NN];
    __shared__ __align__(16) float hp[4][HID];
    __shared__ __align__(16) float hs[HID];
    __shared__ float sx1[MLPH];
    __shared__ float sxf2[MLPH];
    __shared__ float sglo[8];
    __shared__ float smax;
    int b = blockIdx.x;
    int tid = threadIdx.x;
    // stage A: reduce 4 k-slice partials; stage tiny inputs on spare waves
    {
        int o = b * NN + tid;
        sq0[tid] = q0p[o] + q0p[BB * NN + o] + q0p[2 * BB * NN + o] + q0p[3 * BB * NN + o];
        sq1[tid] = q1p[o] + q1p[BB * NN + o] + q1p[2 * BB * NN + o] + q1p[3 * BB * NN + o];
        sw[tid]  = wjp[o] + wjp[BB * NN + o] + wjp[2 * BB * NN + o] + wjp[3 * BB * NN + o];
    }
    if (tid >= 384 && tid < 448) {   // wave 6: batch max over 64 block partials
        float v = bmax[b * 64 + (tid - 384)];
        v = wave_max(v);
        if (tid == 384) smax = v;
    }
    if (tid >= 448 && tid < 512) sx1[tid - 448] = xf1[b * MLPH + (tid - 448)];
    __syncthreads();
    // stage B: hsum, 4-way j-parallel (h = tid&255, jq = tid>>8)
    {
        int h  = tid & 255;
        int jq = tid >> 8;
        float w10 = W1[h * 2], w11 = W1[h * 2 + 1], bb = b1[h];
        float acc = 0.f;
        const float4* q0v4 = (const float4*)&sq0[jq * 256];
        const float4* q1v4 = (const float4*)&sq1[jq * 256];
        const float4* wv4  = (const float4*)&sw[jq * 256];
#pragma unroll 4
        for (int g = 0; g < 64; ++g) {
            float4 q0v = q0v4[g], q1v = q1v4[g], wv = wv4[g];
            acc = fmaf(wv.x, fmaxf(fmaf(q1v.x, w11, fmaf(q0v.x, w10, bb)), 0.f), acc);
            acc = fmaf(wv.y, fmaxf(fmaf(q1v.y, w11, fmaf(q0v.y, w10, bb)), 0.f), acc);
            acc = fmaf(wv.z, fmaxf(fmaf(q1v.z, w11, fmaf(q0v.z, w10, bb)), 0.f), acc);
            acc = fmaf(wv.w, fmaxf(fmaf(q1v.w, w11, fmaf(q0v.w, w10, bb)), 0.f), acc);
        }
        hp[jq][h] = acc;
    }
    __syncthreads();
    // stage C: hs reduce (0..255); MLP layer-2 (256..319); global branch (320..327)
    if (tid < HID) {
        hs[tid] = hp[0][tid] + hp[1][tid] + hp[2][tid] + hp[3][tid];
    } else if (tid < HID + MLPH) {
        int t = tid - HID;
        float a = bm1[t];
        const float* wv = Wm1 + t * MLPH;
#pragma unroll
        for (int k = 0; k < MLPH; ++k) a = fmaf(wv[k], sx1[k], a);
        sxf2[t] = fmaxf(a, 0.f);
    } else if (tid < HID + MLPH + 8) {
        int t = tid - HID - MLPH;
        float avg  = sumsp[b] * (1.0f / NN);
        float dens = 1.0f / sqrtf(smax);
        sglo[t] = fmaxf(fmaf(Wg[t * 2], avg, fmaf(Wg[t * 2 + 1], dens, bg[t])), 0.f);
    }
    __syncthreads();
    // stage D: one wave per output o: E.hs (dot-256) + Wp_mlp.xf2 (dot-64) + glo + consts
    if (tid < 512) {
        int o = tid >> 6, lane = tid & 63;
        const float* Eo = E + o * HID;
        float a = Eo[lane] * hs[lane];
        a = fmaf(Eo[lane + 64],  hs[lane + 64],  a);
        a = fmaf(Eo[lane + 128], hs[lane + 128], a);
        a = fmaf(Eo[lane + 192], hs[lane + 192], a);
        a = fmaf(Wp[o * CATN + lane], sxf2[lane], a);
        a = wave_sum(a);
        if (lane == 0) {
            const float* wg = Wp + o * CATN + MLPH + HID;
#pragma unroll
            for (int g = 0; g < 8; ++g) a = fmaf(wg[g], sglo[g], a);
            out[b * OUTN + o] = a + cE[o] + bp[o];
        }
    }
}

extern "C" void kernel_launch(void* const* d_in, const int* in_sizes, int n_in,
                              void* d_out, int out_size, void* d_ws, size_t ws_size,
                              hipStream_t stream) {
    const float* x   = (const float*)d_in[0];
    const float* W1  = (const float*)d_in[1];
    const float* b1  = (const float*)d_in[2];
    const float* W2  = (const float*)d_in[3];
    const float* b2  = (const float*)d_in[4];
    const float* Wfc = (const float*)d_in[5];
    const float* bfc = (const float*)d_in[6];
    const float* Wg  = (const float*)d_in[7];
    const float* bg  = (const float*)d_in[8];
    const float* Wm0 = (const float*)d_in[9];
    const float* bm0 = (const float*)d_in[10];
    const float* Wm1 = (const float*)d_in[11];
    const float* bm1 = (const float*)d_in[12];
    const float* Wp  = (const float*)d_in[13];
    const float* bp  = (const float*)d_in[14];
    float* out = (float*)d_out;
    float* ws = (float*)d_ws;

    float* degp  = ws;            // 4*32*1024 = 131072
    float* q0p   = ws + 131072;   // 131072
    float* q1p   = ws + 262144;   // 131072
    float* wjp   = ws + 393216;   // 131072
    float* bmax  = ws + 524288;   // 2048
    float* sumsp = ws + 526336;   // 32
    float* xf1   = ws + 526368;   // 2048
    float* E     = ws + 528416;   // 8*256 = 2048
    float* cE    = ws + 530464;   // 8
    // every ws cell is written before it is read -> no zero-init needed.

    kA<<<2568,    256,  0, stream>>>(x, Wm0, bm0, W2, b2, Wfc, bfc, Wp,
                                     degp, bmax, sumsp, xf1, E, cE);
    kB<<<BB * 64, 256,  0, stream>>>(x, degp, q0p, q1p, wjp);
    kF<<<BB,      1024, 0, stream>>>(q0p, q1p, wjp, W1, b1, Wg, bg,
                                     Wm1, bm1, Wp, bp,
                                     xf1, bmax, sumsp, E, cE, out);
}